// Round 6
// baseline (191.084 us; speedup 1.0000x reference)
//
#include <hip/hip_runtime.h>
#include <hip/hip_bf16.h>
#include <math.h>

// Symmetric Hausdorff, B=8, N=M=4096, D=2, fp32.
// Round 6: single fused kernel. Round-5's partial loop (VALU-bound, 2.625
// ops/pair) is kept verbatim; the maxred/final kernels (and their ~10us of
// launch gaps + straggler drains) are replaced by an in-kernel last-block
// reduction: 32 groups of 32 blocks each (group = dir,b,ib-half); the last
// block of each group min-reduces over jc / max-reduces over i (256 KB
// coalesced), atomicMax'es a per-(dir,b) slot; the last group computes the
// final scalar. Device-scope __threadfence around every counter hop (XCD L2s
// are not cross-coherent). Counters+slots zeroed by one tiny hipMemsetAsync
// (slots: 0 is a valid identity, d^2 >= 0; positive-float bits are
// int-monotone). The ~42us fillBuffer in every profile is the harness
// poisoning the 256 MiB workspace inside the timed window — fixed cost.

#define B 8
#define N 4096
#define TPB 256
#define IB 8              // i-points per thread
#define JC 32             // j-chunks per (b,dir)
#define JTILE (N / JC)    // 128 j-points per block
#define NGROUP 32         // (dir, b, ib)
#define BPG 32            // blocks per group (= JC)

__global__ __launch_bounds__(TPB) void hk_main(const float* __restrict__ pred,
                                               const float* __restrict__ target,
                                               int* __restrict__ cnt,    // [32]
                                               int* __restrict__ cnt2,   // [1]
                                               int* __restrict__ slots,  // [16]
                                               float* __restrict__ pw,
                                               float* __restrict__ out) {
    const int bx  = blockIdx.x;        // 0..63: [ib: bit0] x [jc: bits1..5]
    const int ib  = bx & 1;
    const int jc  = bx >> 1;
    const int b   = blockIdx.y;
    const int dir = blockIdx.z;
    const int t   = threadIdx.x;

    __shared__ float4 sQ[JTILE / 2];
    __shared__ float  sred[TPB / 64];
    __shared__ float  sh2[2 * B];
    __shared__ int    sflag, sflag2;

    const float2* __restrict__ P =
        reinterpret_cast<const float2*>(dir == 0 ? pred : target) + (size_t)b * N;
    const float*  __restrict__ Qf =
        (dir == 0 ? target : pred) + (size_t)b * N * 2 + (size_t)jc * JTILE * 2;

    // ---- Stage 1: partial mins over this block's j-chunk (Round-5 loop) ----
    if (t < JTILE / 2)
        sQ[t] = reinterpret_cast<const float4*>(Qf)[t];
    __syncthreads();

    float m2x[IB], m2y[IB], pp[IB], mn[IB];
    const int i0 = ib * (TPB * IB) + t;
    #pragma unroll
    for (int k = 0; k < IB; ++k) {
        float2 p = P[i0 + k * TPB];
        m2x[k] = -2.f * p.x;
        m2y[k] = -2.f * p.y;
        pp[k]  = fmaf(p.x, p.x, p.y * p.y);
        mn[k]  = 3.402823466e38f;
    }

    #pragma unroll 4
    for (int j = 0; j < JTILE / 2; ++j) {
        float4 q = sQ[j];
        float qqa = fmaf(q.x, q.x, q.y * q.y);
        float qqb = fmaf(q.z, q.z, q.w * q.w);
        #pragma unroll
        for (int k = 0; k < IB; ++k) {
            float ta = fmaf(m2x[k], q.x, fmaf(m2y[k], q.y, qqa));
            float tb = fmaf(m2x[k], q.z, fmaf(m2y[k], q.w, qqb));
            mn[k] = fminf(mn[k], fminf(ta, tb));   // v_min3_f32
        }
    }

    float* dst = pw + (size_t)((dir * B + b) * JC + jc) * N;
    #pragma unroll
    for (int k = 0; k < IB; ++k)
        dst[i0 + k * TPB] = mn[k] + pp[k];

    // ---- Arrive: last block of group (dir,b,ib) does the group reduce ----
    __threadfence();                               // release pw stores (device scope)
    if (t == 0) {
        int old = atomicAdd(&cnt[(dir * B + b) * 2 + ib], 1);
        sflag = (old == BPG - 1);
    }
    __syncthreads();
    if (!sflag) return;
    __threadfence();                               // acquire others' pw stores

    // ---- Stage 2: min over 32 jc, max over this half's 2048 i ----
    const float* base = pw + (size_t)((dir * B + b) * JC) * N;
    float mx = -3.402823466e38f;
    #pragma unroll
    for (int k = 0; k < IB; ++k) {
        const int i = ib * (TPB * IB) + t + k * TPB;
        float mnv = base[i];
        #pragma unroll
        for (int j2 = 1; j2 < JC; ++j2)
            mnv = fminf(mnv, base[(size_t)j2 * N + i]);
        mx = fmaxf(mx, mnv);
    }
    #pragma unroll
    for (int off = 32; off > 0; off >>= 1)
        mx = fmaxf(mx, __shfl_down(mx, off, 64));
    if ((t & 63) == 0) sred[t >> 6] = mx;
    __syncthreads();

    if (t == 0) {
        float bm = sred[0];
        #pragma unroll
        for (int w = 1; w < TPB / 64; ++w) bm = fmaxf(bm, sred[w]);
        atomicMax(&slots[dir * B + b], __float_as_int(bm));  // bm >= 0
        __threadfence();                           // release slot before counting
        int old2 = atomicAdd(cnt2, 1);
        sflag2 = (old2 == NGROUP - 1);
    }
    __syncthreads();
    if (!sflag2) return;
    __threadfence();

    // ---- Stage 3: final scalar (runs in exactly one block) ----
    if (t < 2 * B)
        sh2[t] = __int_as_float(atomicMax(&slots[t], 0));  // coherent read
    __syncthreads();
    if (t == 0) {
        float s = 0.f;
        #pragma unroll
        for (int bb = 0; bb < B; ++bb)
            s += sqrtf(fmaxf(fmaxf(sh2[bb], sh2[B + bb]), 0.f));
        out[0] = s * (1.0f / B);
    }
}

extern "C" void kernel_launch(void* const* d_in, const int* in_sizes, int n_in,
                              void* d_out, int out_size, void* d_ws, size_t ws_size,
                              hipStream_t stream) {
    const float* pred   = (const float*)d_in[0];
    const float* target = (const float*)d_in[1];
    float* out = (float*)d_out;

    int*   cnt   = (int*)d_ws;                        // [32]
    int*   cnt2  = (int*)d_ws + 32;                   // [1]
    int*   slots = (int*)d_ws + 64;                   // [16]
    float* pw    = (float*)((char*)d_ws + 1024);      // 8 MB partial mins

    hipMemsetAsync(d_ws, 0, 1024, stream);            // counters + slots

    dim3 g1(64, B, 2);           // 1024 blocks -> 4 blocks/CU, 16 waves/CU
    hk_main<<<g1, TPB, 0, stream>>>(pred, target, cnt, cnt2, slots, pw, out);
}

// Round 7
// 80.053 us; speedup vs baseline: 2.3870x; 2.3870x over previous
//
#include <hip/hip_runtime.h>
#include <hip/hip_bf16.h>
#include <math.h>

// Symmetric Hausdorff, B=8, N=M=4096, D=2, fp32.
// Round 7: REVERT Round-6 fusion (1024 device-scope __threadfence's forced
// pw to HBM + L2 writeback storms: WRITE_SIZE 8.2MB, kernel 143us; the
// 3-kernel pipeline's implicit kernel-boundary release/acquire is the cheap
// coherence mechanism). Back to Round-5 structure, inner loop reworked to
// packed fp32 (VOP3P): the two j-points of each iteration become the two
// halves of <2 x float> registers -> LLVM pattern-matches v_pk_fma_f32
// (gfx90a+; fp32 peak 157 TF = 2x scalar v_fma rate). Per j-iter:
// 1 ds_read_b128 + ~26 VALU (vs 42 scalar) = 1.63 inst/pair.
// Pipeline: hk_partial (1024 blocks) -> hk_maxred (256) -> hk_final (1).
// The ~42us fillBuffer in every profile is the harness poisoning the 256 MiB
// workspace inside the timed window — fixed cost, not ours.

#define B 8
#define N 4096
#define TPB 256
#define IB 8              // i-points per thread
#define JC 32             // j-chunks per (b,dir)
#define JTILE (N / JC)    // 128 j-points per block
#define ITILES (N / TPB)  // 16 i-tiles for the reduce stage

typedef float v2f __attribute__((ext_vector_type(2)));

__global__ __launch_bounds__(TPB) void hk_partial(const float* __restrict__ pred,
                                                  const float* __restrict__ target,
                                                  float* __restrict__ pw) {
    const int bx  = blockIdx.x;        // 0..63: [ib: bit0] x [jc: bits1..5]
    const int ib  = bx & 1;
    const int jc  = bx >> 1;
    const int b   = blockIdx.y;
    const int dir = blockIdx.z;

    const float2* __restrict__ P =
        reinterpret_cast<const float2*>(dir == 0 ? pred : target) + (size_t)b * N;
    const float*  __restrict__ Qf =
        (dir == 0 ? target : pred) + (size_t)b * N * 2 + (size_t)jc * JTILE * 2;

    // Stage this block's 128 j-points as 64 float4 (2 points each). 1 KB LDS.
    __shared__ float4 sQ[JTILE / 2];
    if (threadIdx.x < JTILE / 2)
        sQ[threadIdx.x] = reinterpret_cast<const float4*>(Qf)[threadIdx.x];
    __syncthreads();

    // This thread's IB source points (strided by TPB so pw stores coalesce).
    // m2x/m2y kept as splat pairs so the packed FMAs need no lane shuffling.
    v2f m2x[IB], m2y[IB];
    float pp[IB], mn[IB];
    const int i0 = ib * (TPB * IB) + threadIdx.x;
    #pragma unroll
    for (int k = 0; k < IB; ++k) {
        float2 p = P[i0 + k * TPB];
        float ax = -2.f * p.x, ay = -2.f * p.y;
        m2x[k] = (v2f){ax, ax};
        m2y[k] = (v2f){ay, ay};
        pp[k]  = fmaf(p.x, p.x, p.y * p.y);
        mn[k]  = 3.402823466e38f;
    }

    // min_j(|q|^2 - 2 p.q), two j-points per packed register.
    // Per iter: 1 broadcast b128 + 2 pk (qq) + 8*(2 pk_fma + 1 v_min3).
    #pragma unroll 4
    for (int j = 0; j < JTILE / 2; ++j) {
        float4 q = sQ[j];
        v2f qx = (v2f){q.x, q.z};
        v2f qy = (v2f){q.y, q.w};
        v2f qq = __builtin_elementwise_fma(qx, qx, qy * qy);
        #pragma unroll
        for (int k = 0; k < IB; ++k) {
            v2f t = __builtin_elementwise_fma(m2y[k], qy, qq);
            t     = __builtin_elementwise_fma(m2x[k], qx, t);
            mn[k] = fminf(mn[k], fminf(t.x, t.y));   // v_min3_f32
        }
    }

    // Partial min for this j-chunk, |p|^2 restored. Layout: [dir][b][jc][i].
    float* dst = pw + (size_t)((dir * B + b) * JC + jc) * N;
    #pragma unroll
    for (int k = 0; k < IB; ++k)
        dst[i0 + k * TPB] = mn[k] + pp[k];
}

// One block per (i-tile, b, dir): min over 32 jc (coalesced), block max-reduce,
// write to a private slot — no atomics, no init required.
__global__ __launch_bounds__(TPB) void hk_maxred(const float* __restrict__ pw,
                                                 float* __restrict__ pw2) {
    const int tile = blockIdx.x;
    const int b    = blockIdx.y;
    const int dir  = blockIdx.z;
    const int t    = threadIdx.x;

    const float* base = pw + (size_t)((dir * B + b) * JC) * N + tile * TPB + t;
    float mnv = base[0];
    #pragma unroll
    for (int jc = 1; jc < JC; ++jc) mnv = fminf(mnv, base[(size_t)jc * N]);

    float mx = mnv;
    #pragma unroll
    for (int off = 32; off > 0; off >>= 1)
        mx = fmaxf(mx, __shfl_down(mx, off, 64));

    __shared__ float sred[TPB / 64];
    if ((t & 63) == 0) sred[t >> 6] = mx;
    __syncthreads();
    if (t == 0) {
        float bm = sred[0];
        #pragma unroll
        for (int w = 1; w < TPB / 64; ++w) bm = fmaxf(bm, sred[w]);
        pw2[(dir * B + b) * ITILES + tile] = bm;   // [dir][b][tile]
    }
}

// Single block: 256 slots -> 16 (dir,b) maxes -> mean over b of sqrt(max(dirs)).
__global__ __launch_bounds__(64) void hk_final(const float* __restrict__ pw2,
                                               float* __restrict__ out) {
    const int t = threadIdx.x;
    __shared__ float h2[2 * B];
    if (t < 2 * B) {
        float mx = pw2[t * ITILES];
        #pragma unroll
        for (int k = 1; k < ITILES; ++k) mx = fmaxf(mx, pw2[t * ITILES + k]);
        h2[t] = mx;
    }
    __syncthreads();
    if (t == 0) {
        float s = 0.f;
        #pragma unroll
        for (int b = 0; b < B; ++b)
            s += sqrtf(fmaxf(fmaxf(h2[b], h2[B + b]), 0.f));
        out[0] = s * (1.0f / B);
    }
}

extern "C" void kernel_launch(void* const* d_in, const int* in_sizes, int n_in,
                              void* d_out, int out_size, void* d_ws, size_t ws_size,
                              hipStream_t stream) {
    const float* pred   = (const float*)d_in[0];
    const float* target = (const float*)d_in[1];
    float* out = (float*)d_out;
    float* pw  = (float*)d_ws;                       // 2*8*32*4096 floats = 8 MB
    float* pw2 = (float*)((char*)d_ws + (size_t)2 * B * JC * N * sizeof(float)); // 256 floats

    dim3 g1(64, B, 2);           // 1024 blocks -> 4 blocks/CU, 16 waves/CU
    hk_partial<<<g1, TPB, 0, stream>>>(pred, target, pw);
    dim3 g2(ITILES, B, 2);       // 256 blocks
    hk_maxred<<<g2, TPB, 0, stream>>>(pw, pw2);
    hk_final<<<1, 64, 0, stream>>>(pw2, out);
}